// Round 5
// baseline (236.863 us; speedup 1.0000x reference)
//
#include <hip/hip_runtime.h>
#include <hip/hip_bf16.h>

#define B_    32
#define LD_   512
#define LQ_   32
#define E_    300
#define NF_   4
#define D_    304
#define M_    16
#define ALPHA_ 0.9f
#define CIN_  1212          // 3*D + E
#define KP1_  1280          // CIN padded to multiple of 64
#define NCOL_ 1056          // 33 columns * 32 batches
#define NPAD_ 1088          // 17 * 64
#define PPL_  9
#define NEG_N_ 128

typedef short short8 __attribute__((ext_vector_type(8)));
typedef float f32x4 __attribute__((ext_vector_type(4)));

__device__ __forceinline__ unsigned short f2bf(float f) {
    unsigned int x = __float_as_uint(f);
    unsigned int r = (x + 0x7FFFu + ((x >> 16) & 1u)) >> 16;
    return (unsigned short)r;
}

// ---------------------------------------------------------------------------
// prep v2: dense-gather column builder.
//   [0,160)     (batch, 60-ch slice) blocks: gather doc slice ONCE to LDS
//               (512x60 f32), then 33 cols x 3 parts as 16-tap FIRs from LDS;
//               query FOFE computed once per batch slice (was 33x).
//               Cuts emb gather traffic ~100 MB -> ~21 MB.
//   [160,1104)  weight fp32->bf16 (unchanged code, rebased ids)
//   [1104,1136) zero Ft pad rows 1056..1087
//   1136        zero zbuf + done counter
// ---------------------------------------------------------------------------
__global__ __launch_bounds__(320) void prep(
    const int* __restrict__ doc, const float* __restrict__ doc_f,
    const int* __restrict__ query,
    const int* __restrict__ target_s, const int* __restrict__ target_e,
    const float* __restrict__ emb,
    const int* __restrict__ rand_length, const int* __restrict__ rand_position,
    const float* __restrict__ W1, const float* __restrict__ W2,
    const float* __restrict__ W3, const float* __restrict__ W4,
    unsigned short* __restrict__ W1b, unsigned short* __restrict__ W2b,
    unsigned short* __restrict__ W3b, unsigned short* __restrict__ W4b,
    unsigned short* __restrict__ Ft, float* __restrict__ zbuf,
    unsigned* __restrict__ done)
{
    int bid = blockIdx.x;
    int tid = threadIdx.x;

    if (bid < 160) {
        int b = bid / 5, slice = bid % 5;
        int ch0 = slice * 60;
        __shared__ float Ds[512][60];   // dense doc-slice (emb channels)
        __shared__ float Fs[512][4];    // doc_f (used by slice 4 only)
        __shared__ float Qs[32][60];    // query rows slice
        __shared__ int   s_doc[512];
        __shared__ float s_aw[16];
        __shared__ float s_qw[32];

        for (int r = tid; r < LD_; r += 320) s_doc[r] = doc[b * LD_ + r];
        if (tid < 16) s_aw[tid] = powf(ALPHA_, (float)tid);
        else if (tid < 48) s_qw[tid - 16] = powf(ALPHA_, (float)(LQ_ - 1 - (tid - 16)));
        __syncthreads();

        // dense gather: 512 rows x 15 float4 (240B per row slice, aligned)
        for (int idx = tid; idx < 512 * 15; idx += 320) {
            int r = idx / 15, f = idx - r * 15;
            *(float4*)&Ds[r][f * 4] =
                *(const float4*)(emb + (size_t)s_doc[r] * E_ + ch0 + f * 4);
        }
        // query rows: 32 x 15 float4
        for (int idx = tid; idx < 32 * 15; idx += 320) {
            int r = idx / 15, f = idx - r * 15;
            *(float4*)&Qs[r][f * 4] =
                *(const float4*)(emb + (size_t)query[b * LQ_ + r] * E_ + ch0 + f * 4);
        }
        if (slice == 4) {
            for (int r = tid; r < LD_; r += 320)
                *(float4*)&Fs[r][0] = *(const float4*)(doc_f + ((size_t)b * LD_ + r) * NF_);
        }
        __syncthreads();

        // FIR phase: wave w handles tasks jp = w, w+5, ... (99 = 33 cols x 3 parts)
        int c = tid & 63;          // channel lane (c<60 emb; c>=60 doc_f on slice 4)
        int slot = tid >> 6;       // wave id 0..4
        for (int jp = slot; jp < 99; jp += 5) {
            int j = jp / 3, part = jp - j * 3;
            int A, kl;
            if (j == 0) {
                int ts = target_s[b], te = target_e[b];
                A = (part == 0) ? ts : te;
                kl = te - ts;
            } else {
                int jj = j - 1, r = jj / PPL_, p = jj - r * PPL_;
                int rl = rand_length[r], rp = rand_position[r * PPL_ + p];
                A = (part == 2) ? (rp + rl) : rp;
                kl = rl;
            }
            float acc = 0.f;
            #pragma unroll
            for (int k = 0; k < 16; ++k) {
                int t; float valid;
                if (part == 0)      { t = A - 1 - k; valid = (t >= 0) ? 1.f : 0.f; }
                else if (part == 1) { t = A - k;     valid = (k <= kl && t >= 0) ? 1.f : 0.f; }
                else                { t = A + 1 + k; valid = (t < LD_) ? 1.f : 0.f; }
                t = min(max(t, 0), LD_ - 1);
                float w = valid * s_aw[k];
                float v = (c < 60) ? Ds[t][c] : Fs[t][c & 3];
                acc += w * v;
            }
            if (c < 60 || slice == 4) {
                int ch = (c < 60) ? (ch0 + c) : (300 + (c - 60));
                Ft[(size_t)(b * 33 + j) * KP1_ + part * 304 + ch] = f2bf(acc);
            }
        }

        // query FOFE once; broadcast to the batch's 33 columns
        if (tid < 60) {
            float qa = 0.f;
            for (int i = 0; i < 32; ++i) qa += s_qw[i] * Qs[i][tid];
            unsigned short qb = f2bf(qa);
            for (int j = 0; j < 33; ++j)
                Ft[(size_t)(b * 33 + j) * KP1_ + 912 + ch0 + tid] = qb;
        }

        // zero K-padding cols 1212..1279 for this batch's 33 columns
        if (slice == 0) {
            for (int idx = tid; idx < 33 * 34; idx += 320) {
                int j = idx / 34, u = idx - j * 34;
                *(unsigned int*)(Ft + (size_t)(b * 33 + j) * KP1_ + 1212 + u * 2) = 0u;
            }
        }
    } else if (bid < 1104) {
        const long n1 = 1024L * 320;                 // W1 groups (K-padded)
        const long n2 = 1024L * 1024L / 4;
        const long n4 = 512L * 1024L / 4;
        const long total = n1 + 2 * n2 + n4;
        long stride = 944L * 320L;
        for (long i = (long)(bid - 160) * 320L + tid; i < total; i += stride) {
            ushort4 o;
            if (i < n1) {
                long m = i / 320; int k4 = (int)(i - m * 320);
                if (k4 < 303) {
                    float4 v = *(const float4*)(W1 + m * CIN_ + k4 * 4);
                    o.x = f2bf(v.x); o.y = f2bf(v.y); o.z = f2bf(v.z); o.w = f2bf(v.w);
                } else { o.x = 0; o.y = 0; o.z = 0; o.w = 0; }
                *(ushort4*)(W1b + i * 4) = o;
            } else if (i < n1 + n2) {
                long j = i - n1;
                float4 v = *(const float4*)(W2 + j * 4);
                o.x = f2bf(v.x); o.y = f2bf(v.y); o.z = f2bf(v.z); o.w = f2bf(v.w);
                *(ushort4*)(W2b + j * 4) = o;
            } else if (i < n1 + 2 * n2) {
                long j = i - n1 - n2;
                float4 v = *(const float4*)(W3 + j * 4);
                o.x = f2bf(v.x); o.y = f2bf(v.y); o.z = f2bf(v.z); o.w = f2bf(v.w);
                *(ushort4*)(W3b + j * 4) = o;
            } else {
                long j = i - n1 - 2 * n2;
                float4 v = *(const float4*)(W4 + j * 4);
                o.x = f2bf(v.x); o.y = f2bf(v.y); o.z = f2bf(v.z); o.w = f2bf(v.w);
                *(ushort4*)(W4b + j * 4) = o;
            }
        }
    } else if (bid < 1136) {
        int row = NCOL_ + (bid - 1104);   // 1056..1087
        ushort4 z; z.x = 0; z.y = 0; z.z = 0; z.w = 0;
        *(ushort4*)(Ft + (size_t)row * KP1_ + tid * 4) = z;
    } else {
        for (int i = tid; i < NPAD_; i += 320) zbuf[i] = 0.f;
        if (tid < 8) done[tid] = 0u;
    }
}

// ---------------------------------------------------------------------------
// R0-proven GEMM core (measured 189.97 us total): 64x64 tile, BK=64,
// double-buffered LDS, 4 waves = 2x2 quadrants of 32x32, each 2x2 of
// 16x16x32 MFMA.  Byte-identical to the round-0 baseline.
// ---------------------------------------------------------------------------
struct GemmS { unsigned short A[2][64][72]; unsigned short B[2][64][72]; };

__device__ __forceinline__ void gemm_core(
    const unsigned short* __restrict__ A,
    const unsigned short* __restrict__ Bm,
    int K, int m0, int n0, GemmS& sh, f32x4 acc[4])
{
    int tid = threadIdx.x;
    int w = tid >> 6, lane = tid & 63;
    int wm = (w >> 1) * 32, wn = (w & 1) * 32;
    int lr = tid >> 2;
    int ls = (tid & 3) * 16;
    int fr = lane & 15, fk = (lane >> 4) * 8;

    const unsigned short* Arow = A + (size_t)(m0 + lr) * K + ls;
    const unsigned short* Brow = Bm + (size_t)(n0 + lr) * K + ls;

    #pragma unroll
    for (int t = 0; t < 4; ++t) { acc[t][0]=0.f; acc[t][1]=0.f; acc[t][2]=0.f; acc[t][3]=0.f; }

    int nk = K >> 6;
    *(uint4*)&sh.A[0][lr][ls]     = *(const uint4*)(Arow);
    *(uint4*)&sh.A[0][lr][ls + 8] = *(const uint4*)(Arow + 8);
    *(uint4*)&sh.B[0][lr][ls]     = *(const uint4*)(Brow);
    *(uint4*)&sh.B[0][lr][ls + 8] = *(const uint4*)(Brow + 8);
    __syncthreads();
    int cur = 0;
    for (int i = 0; i < nk; ++i) {
        uint4 na0, na1, nb0, nb1;
        bool more = (i + 1 < nk);
        if (more) {
            const unsigned short* An = Arow + (size_t)(i + 1) * 64;
            const unsigned short* Bn = Brow + (size_t)(i + 1) * 64;
            na0 = *(const uint4*)(An);
            na1 = *(const uint4*)(An + 8);
            nb0 = *(const uint4*)(Bn);
            nb1 = *(const uint4*)(Bn + 8);
        }
        #pragma unroll
        for (int s = 0; s < 2; ++s) {
            short8 fa0 = *(const short8*)&sh.A[cur][wm + fr][s * 32 + fk];
            short8 fa1 = *(const short8*)&sh.A[cur][wm + 16 + fr][s * 32 + fk];
            short8 fb0 = *(const short8*)&sh.B[cur][wn + fr][s * 32 + fk];
            short8 fb1 = *(const short8*)&sh.B[cur][wn + 16 + fr][s * 32 + fk];
            acc[0] = __builtin_amdgcn_mfma_f32_16x16x32_bf16(fa0, fb0, acc[0], 0, 0, 0);
            acc[1] = __builtin_amdgcn_mfma_f32_16x16x32_bf16(fa0, fb1, acc[1], 0, 0, 0);
            acc[2] = __builtin_amdgcn_mfma_f32_16x16x32_bf16(fa1, fb0, acc[2], 0, 0, 0);
            acc[3] = __builtin_amdgcn_mfma_f32_16x16x32_bf16(fa1, fb1, acc[3], 0, 0, 0);
        }
        if (more) {
            int nb = cur ^ 1;
            *(uint4*)&sh.A[nb][lr][ls]     = na0;
            *(uint4*)&sh.A[nb][lr][ls + 8] = na1;
            *(uint4*)&sh.B[nb][lr][ls]     = nb0;
            *(uint4*)&sh.B[nb][lr][ls + 8] = nb1;
        }
        __syncthreads();
        cur ^= 1;
    }
}

__global__ __launch_bounds__(256) void gemm_relu(
    const unsigned short* __restrict__ A,
    const unsigned short* __restrict__ Bm,
    unsigned short* __restrict__ C, int M, int K)
{
    __shared__ GemmS sh;
    int m0 = blockIdx.x * 64, n0 = blockIdx.y * 64;
    f32x4 acc[4];
    gemm_core(A, Bm, K, m0, n0, sh, acc);
    int tid = threadIdx.x;
    int w = tid >> 6, lane = tid & 63;
    int wm = (w >> 1) * 32, wn = (w & 1) * 32;
    int rbase = (lane >> 4) * 4;
    int cb = lane & 15;
    #pragma unroll
    for (int t = 0; t < 4; ++t) {
        int MT = t >> 1, NT = t & 1;
        int m = m0 + wm + MT * 16 + rbase;
        int n = n0 + wn + NT * 16 + cb;
        ushort4 o;
        o.x = f2bf(fmaxf(acc[t][0], 0.f));
        o.y = f2bf(fmaxf(acc[t][1], 0.f));
        o.z = f2bf(fmaxf(acc[t][2], 0.f));
        o.w = f2bf(fmaxf(acc[t][3], 0.f));
        *(ushort4*)(C + (size_t)n * M + m) = o;
    }
}

// ---------------------------------------------------------------------------
// L4 + score partials + loss-by-last-block. grid (8,17) = 136 blocks.
// ---------------------------------------------------------------------------
__global__ __launch_bounds__(256) void gemm4_score_loss(
    const unsigned short* __restrict__ A,
    const unsigned short* __restrict__ Bm,
    const float* __restrict__ W5, const int* __restrict__ rand_idx,
    float* __restrict__ zbuf, unsigned* __restrict__ done,
    float* __restrict__ out, int M, int K)
{
    __shared__ GemmS sh;
    __shared__ int s_flag;
    __shared__ int s_cnt[32];
    __shared__ float s_red[256];
    int m0 = blockIdx.x * 64, n0 = blockIdx.y * 64;
    f32x4 acc[4];
    gemm_core(A, Bm, K, m0, n0, sh, acc);
    int tid = threadIdx.x;
    int w = tid >> 6, lane = tid & 63;
    int wm = (w >> 1) * 32, wn = (w & 1) * 32;
    int fr = lane & 15, fq = lane >> 4;
    #pragma unroll
    for (int NT = 0; NT < 2; ++NT) {
        float p = 0.f;
        #pragma unroll
        for (int MT = 0; MT < 2; ++MT) {
            const f32x4 a = acc[MT * 2 + NT];
            int mb = m0 + wm + MT * 16 + fq * 4;
            p += fmaxf(a[0], 0.f) * W5[mb]
               + fmaxf(a[1], 0.f) * W5[mb + 1]
               + fmaxf(a[2], 0.f) * W5[mb + 2]
               + fmaxf(a[3], 0.f) * W5[mb + 3];
        }
        p += __shfl_down(p, 32);
        p += __shfl_down(p, 16);
        if (fq == 0) {
            int n = n0 + wn + NT * 16 + fr;
            atomicAdd(&zbuf[n], p);
        }
    }
    __syncthreads();   // drains vmcnt: this block's zbuf atomics complete
    if (tid == 0) {
        unsigned old = __hip_atomic_fetch_add(done, 1u, __ATOMIC_ACQ_REL,
                                              __HIP_MEMORY_SCOPE_AGENT);
        s_flag = (old == 8 * 17 - 1) ? 1 : 0;
    }
    __syncthreads();
    if (s_flag) {      // last block: all zbuf adds visible (acquire on done)
        if (tid < 32) s_cnt[tid] = 0;
        __syncthreads();
        if (tid < NEG_N_) atomicAdd(&s_cnt[rand_idx[tid]], 1);
        __syncthreads();
        float accv = 0.f;
        for (int c = tid; c < NCOL_; c += 256) {
            float z = __hip_atomic_load(&zbuf[c], __ATOMIC_ACQUIRE,
                                        __HIP_MEMORY_SCOPE_AGENT);
            float s = 1.f / (1.f + expf(-z));
            int c33 = c % 33;
            if (c33 == 0) { float d = s - 1.f; accv += 128.f * d * d; }
            else          { accv += (float)s_cnt[c33 - 1] * s * s; }
        }
        s_red[tid] = accv;
        __syncthreads();
        for (int o = 128; o > 0; o >>= 1) {
            if (tid < o) s_red[tid] += s_red[tid + o];
            __syncthreads();
        }
        if (tid == 0) out[0] = s_red[0];
    }
}

extern "C" void kernel_launch(void* const* d_in, const int* in_sizes, int n_in,
                              void* d_out, int out_size, void* d_ws, size_t ws_size,
                              hipStream_t stream)
{
    const int*   doc        = (const int*)d_in[0];
    const float* doc_f      = (const float*)d_in[1];
    const int*   query      = (const int*)d_in[2];
    const int*   target_s   = (const int*)d_in[3];
    const int*   target_e   = (const int*)d_in[4];
    const float* emb        = (const float*)d_in[7];
    const float* W1         = (const float*)d_in[8];
    const float* W2         = (const float*)d_in[9];
    const float* W3         = (const float*)d_in[10];
    const float* W4         = (const float*)d_in[11];
    const float* W5         = (const float*)d_in[12];
    const int*   rand_length   = (const int*)d_in[13];
    const int*   rand_position = (const int*)d_in[14];
    const int*   rand_idx      = (const int*)d_in[15];

    char* ws = (char*)d_ws;
    size_t off = 0;
    auto alloc = [&](size_t bytes) {
        void* p = ws + off;
        off = (off + bytes + 255) & ~(size_t)255;
        return p;
    };
    unsigned short* W1b = (unsigned short*)alloc((size_t)1024 * KP1_ * 2);
    unsigned short* W2b = (unsigned short*)alloc((size_t)1024 * 1024 * 2);
    unsigned short* W3b = (unsigned short*)alloc((size_t)1024 * 1024 * 2);
    unsigned short* W4b = (unsigned short*)alloc((size_t)512 * 1024 * 2);
    unsigned short* Ft  = (unsigned short*)alloc((size_t)NPAD_ * KP1_ * 2);
    unsigned short* hA  = (unsigned short*)alloc((size_t)NPAD_ * 1024 * 2);
    unsigned short* hB  = (unsigned short*)alloc((size_t)NPAD_ * 1024 * 2);
    float*    zbuf      = (float*)alloc((size_t)NPAD_ * sizeof(float));
    unsigned* done      = (unsigned*)alloc(256);
    (void)ws_size; (void)in_sizes; (void)n_in; (void)out_size;

    prep<<<dim3(1137), dim3(320), 0, stream>>>(
        doc, doc_f, query, target_s, target_e, emb,
        rand_length, rand_position,
        W1, W2, W3, W4, W1b, W2b, W3b, W4b, Ft, zbuf, done);

    gemm_relu<<<dim3(16, 17), dim3(256), 0, stream>>>(W1b, Ft, hA, 1024, KP1_);
    gemm_relu<<<dim3(16, 17), dim3(256), 0, stream>>>(W2b, hA, hB, 1024, 1024);
    gemm_relu<<<dim3(16, 17), dim3(256), 0, stream>>>(W3b, hB, hA, 1024, 1024);
    gemm4_score_loss<<<dim3(8, 17), dim3(256), 0, stream>>>(
        W4b, hA, W5, rand_idx, zbuf, done, (float*)d_out, 512, 1024);
}

// Round 6
// 185.527 us; speedup vs baseline: 1.2767x; 1.2767x over previous
//
#include <hip/hip_runtime.h>
#include <hip/hip_bf16.h>

#define B_    32
#define LD_   512
#define LQ_   32
#define E_    300
#define NF_   4
#define D_    304
#define M_    16
#define ALPHA_ 0.9f
#define CIN_  1212          // 3*D + E
#define KP1_  1280          // CIN padded to multiple of 64
#define NCOL_ 1056          // 33 columns * 32 batches
#define NPAD_ 1088          // 17 * 64
#define PPL_  9
#define NEG_N_ 128

typedef short short8 __attribute__((ext_vector_type(8)));
typedef float f32x4 __attribute__((ext_vector_type(4)));

__device__ __forceinline__ unsigned short f2bf(float f) {
    unsigned int x = __float_as_uint(f);
    unsigned int r = (x + 0x7FFFu + ((x >> 16) & 1u)) >> 16;
    return (unsigned short)r;
}

// ---------------------------------------------------------------------------
// prep v3 = R0 prep with two cuts:
//   * query FOFE computed ONCE per batch (col==0 block writes all 33 rows;
//     identical arithmetic -> bit-identical Ft)
//   * weight conversion: W1 ONLY (W2/W3/W4 ride on gemm1/2/3)
// Branches:
//   [0,1056)     feature columns
//   [1056,2080)  W1 fp32->bf16, one ushort4 group per thread (direct index)
//   [2080,2112)  zero Ft pad rows 1056..1087
//   2112         zero zbuf + done counter
// ---------------------------------------------------------------------------
__global__ __launch_bounds__(320) void prep(
    const int* __restrict__ doc, const float* __restrict__ doc_f,
    const int* __restrict__ query,
    const int* __restrict__ target_s, const int* __restrict__ target_e,
    const float* __restrict__ emb,
    const int* __restrict__ rand_length, const int* __restrict__ rand_position,
    const float* __restrict__ W1,
    unsigned short* __restrict__ W1b,
    unsigned short* __restrict__ Ft, float* __restrict__ zbuf,
    unsigned* __restrict__ done)
{
    int bid = blockIdx.x;
    int tid = threadIdx.x;

    if (bid < NCOL_) {
        int b = bid / 33;
        int col = bid % 33;
        __shared__ int   s_t[3][16];
        __shared__ float s_w[3][16];
        __shared__ int   s_row[3][16];
        if (tid < 48) {
            int part = tid >> 4, k = tid & 15;
            int t; float valid;
            if (col == 0) {
                int ts = target_s[b], te = target_e[b];
                int span = te - ts;
                if (part == 0)      { t = ts - 1 - k;  valid = (t >= 0) ? 1.f : 0.f; }
                else if (part == 1) { t = te - k;      valid = (k <= span && t >= 0) ? 1.f : 0.f; }
                else                { t = te + 1 + k;  valid = (t < LD_) ? 1.f : 0.f; }
            } else {
                int j = col - 1;
                int r = j / PPL_, p = j - r * PPL_;
                int rl = rand_length[r];
                int rp = rand_position[r * PPL_ + p];
                if (part == 0)      { t = rp - 1 - k;      valid = (t >= 0) ? 1.f : 0.f; }
                else if (part == 1) { t = rp - k;          valid = (k <= rl && t >= 0) ? 1.f : 0.f; }
                else                { t = rp + rl + 1 + k; valid = (t < LD_) ? 1.f : 0.f; }
            }
            float w = (valid != 0.f) ? powf(ALPHA_, (float)k) : 0.f;
            t = min(max(t, 0), LD_ - 1);
            s_t[part][k] = t;
            s_w[part][k] = w;
            s_row[part][k] = doc[b * LD_ + t];
        }
        __syncthreads();

        unsigned short* out = Ft + (size_t)bid * KP1_;
        int g = tid;                       // 320 groups of 4 elements (K=1280)
        if (g < 228) {                     // doc parts: 3 * 76 groups
            int part = g / 76;
            int g2 = g - part * 76;
            int cc = g2 * 4;
            float ax = 0.f, ay = 0.f, az = 0.f, aw = 0.f;
            if (cc < 300) {
                for (int i = 0; i < 16; ++i) {
                    float4 v = *(const float4*)(emb + (size_t)s_row[part][i] * E_ + cc);
                    float wv = s_w[part][i];
                    ax += wv * v.x; ay += wv * v.y; az += wv * v.z; aw += wv * v.w;
                }
            } else {
                for (int i = 0; i < 16; ++i) {
                    float4 v = *(const float4*)(doc_f + ((size_t)b * LD_ + s_t[part][i]) * NF_);
                    float wv = s_w[part][i];
                    ax += wv * v.x; ay += wv * v.y; az += wv * v.z; aw += wv * v.w;
                }
            }
            ushort4 o; o.x = f2bf(ax); o.y = f2bf(ay); o.z = f2bf(az); o.w = f2bf(aw);
            *(ushort4*)(out + 4 * g) = o;
        } else if (g < 303) {              // query FOFE, ce = (g-228)*4
            if (col == 0) {                // once per batch; broadcast to 33 rows
                int ce = (g - 228) * 4;
                float ax = 0.f, ay = 0.f, az = 0.f, aw = 0.f;
                float wv = powf(ALPHA_, (float)(LQ_ - 1));
                for (int i = 0; i < 32; ++i) {
                    int row = query[b * LQ_ + i];
                    float4 v = *(const float4*)(emb + (size_t)row * E_ + ce);
                    ax += wv * v.x; ay += wv * v.y; az += wv * v.z; aw += wv * v.w;
                    wv *= (1.0f / ALPHA_);
                }
                ushort4 o; o.x = f2bf(ax); o.y = f2bf(ay); o.z = f2bf(az); o.w = f2bf(aw);
                for (int j = 0; j < 33; ++j)
                    *(ushort4*)(Ft + (size_t)(bid + j) * KP1_ + 4 * g) = o;
            }
        } else {                           // K padding 1212..1279
            ushort4 z; z.x = 0; z.y = 0; z.z = 0; z.w = 0;
            *(ushort4*)(out + 4 * g) = z;
        }
    } else if (bid < 2080) {               // W1: one ushort4 group per thread
        long i = (long)(bid - NCOL_) * 320L + tid;   // [0, 327680)
        long m = i / 320; int k4 = (int)(i - m * 320);
        ushort4 o;
        if (k4 < 303) {
            float4 v = *(const float4*)(W1 + m * CIN_ + k4 * 4);
            o.x = f2bf(v.x); o.y = f2bf(v.y); o.z = f2bf(v.z); o.w = f2bf(v.w);
        } else { o.x = 0; o.y = 0; o.z = 0; o.w = 0; }
        *(ushort4*)(W1b + i * 4) = o;
    } else if (bid < 2112) {
        int row = NCOL_ + (bid - 2080);    // 1056..1087
        ushort4 z; z.x = 0; z.y = 0; z.z = 0; z.w = 0;
        *(ushort4*)(Ft + (size_t)row * KP1_ + tid * 4) = z;
    } else {
        for (int i = tid; i < NPAD_; i += 320) zbuf[i] = 0.f;
        if (tid < 8) done[tid] = 0u;
    }
}

// ---------------------------------------------------------------------------
// R0-proven GEMM core (189.97 us total): 64x64 tile, BK=64, double-buffered
// LDS, 4 waves = 2x2 quadrants of 32x32, each 2x2 of 16x16x32 MFMA.
// ---------------------------------------------------------------------------
struct GemmS { unsigned short A[2][64][72]; unsigned short B[2][64][72]; };

__device__ __forceinline__ void gemm_core(
    const unsigned short* __restrict__ A,
    const unsigned short* __restrict__ Bm,
    int K, int m0, int n0, GemmS& sh, f32x4 acc[4])
{
    int tid = threadIdx.x;
    int w = tid >> 6, lane = tid & 63;
    int wm = (w >> 1) * 32, wn = (w & 1) * 32;
    int lr = tid >> 2;
    int ls = (tid & 3) * 16;
    int fr = lane & 15, fk = (lane >> 4) * 8;

    const unsigned short* Arow = A + (size_t)(m0 + lr) * K + ls;
    const unsigned short* Brow = Bm + (size_t)(n0 + lr) * K + ls;

    #pragma unroll
    for (int t = 0; t < 4; ++t) { acc[t][0]=0.f; acc[t][1]=0.f; acc[t][2]=0.f; acc[t][3]=0.f; }

    int nk = K >> 6;
    *(uint4*)&sh.A[0][lr][ls]     = *(const uint4*)(Arow);
    *(uint4*)&sh.A[0][lr][ls + 8] = *(const uint4*)(Arow + 8);
    *(uint4*)&sh.B[0][lr][ls]     = *(const uint4*)(Brow);
    *(uint4*)&sh.B[0][lr][ls + 8] = *(const uint4*)(Brow + 8);
    __syncthreads();
    int cur = 0;
    for (int i = 0; i < nk; ++i) {
        uint4 na0, na1, nb0, nb1;
        bool more = (i + 1 < nk);
        if (more) {
            const unsigned short* An = Arow + (size_t)(i + 1) * 64;
            const unsigned short* Bn = Brow + (size_t)(i + 1) * 64;
            na0 = *(const uint4*)(An);
            na1 = *(const uint4*)(An + 8);
            nb0 = *(const uint4*)(Bn);
            nb1 = *(const uint4*)(Bn + 8);
        }
        #pragma unroll
        for (int s = 0; s < 2; ++s) {
            short8 fa0 = *(const short8*)&sh.A[cur][wm + fr][s * 32 + fk];
            short8 fa1 = *(const short8*)&sh.A[cur][wm + 16 + fr][s * 32 + fk];
            short8 fb0 = *(const short8*)&sh.B[cur][wn + fr][s * 32 + fk];
            short8 fb1 = *(const short8*)&sh.B[cur][wn + 16 + fr][s * 32 + fk];
            acc[0] = __builtin_amdgcn_mfma_f32_16x16x32_bf16(fa0, fb0, acc[0], 0, 0, 0);
            acc[1] = __builtin_amdgcn_mfma_f32_16x16x32_bf16(fa0, fb1, acc[1], 0, 0, 0);
            acc[2] = __builtin_amdgcn_mfma_f32_16x16x32_bf16(fa1, fb0, acc[2], 0, 0, 0);
            acc[3] = __builtin_amdgcn_mfma_f32_16x16x32_bf16(fa1, fb1, acc[3], 0, 0, 0);
        }
        if (more) {
            int nb = cur ^ 1;
            *(uint4*)&sh.A[nb][lr][ls]     = na0;
            *(uint4*)&sh.A[nb][lr][ls + 8] = na1;
            *(uint4*)&sh.B[nb][lr][ls]     = nb0;
            *(uint4*)&sh.B[nb][lr][ls + 8] = nb1;
        }
        __syncthreads();
        cur ^= 1;
    }
}

// ---------------------------------------------------------------------------
// gemm_relu + piggyback weight conversion: flat grid of 272 tile blocks +
// 64 converter blocks (blocks 272..335 convert the NEXT layer's weights;
// they land as second-round dispatches on CUs that otherwise idle while
// CUs 0..15 run their second tile -> conversion hides under the GEMM).
// Stream order guarantees Wnb is complete before the next kernel reads it.
// ---------------------------------------------------------------------------
__global__ __launch_bounds__(256) void gemm_relu(
    const unsigned short* __restrict__ A,
    const unsigned short* __restrict__ Bm,
    unsigned short* __restrict__ C, int M, int K,
    const float* __restrict__ Wn, unsigned short* __restrict__ Wnb,
    int conv_groups)
{
    __shared__ GemmS sh;
    int bid = blockIdx.x;
    int tid = threadIdx.x;
    if (bid >= 272) {                      // converter blocks
        for (long i = (long)(bid - 272) * 256 + tid; i < conv_groups;
             i += 64L * 256) {
            float4 v = *(const float4*)(Wn + i * 4);
            ushort4 o;
            o.x = f2bf(v.x); o.y = f2bf(v.y); o.z = f2bf(v.z); o.w = f2bf(v.w);
            *(ushort4*)(Wnb + i * 4) = o;
        }
        return;
    }
    int m0 = (bid & 15) * 64, n0 = (bid >> 4) * 64;
    f32x4 acc[4];
    gemm_core(A, Bm, K, m0, n0, sh, acc);
    int w = tid >> 6, lane = tid & 63;
    int wm = (w >> 1) * 32, wn = (w & 1) * 32;
    int rbase = (lane >> 4) * 4;
    int cb = lane & 15;
    #pragma unroll
    for (int t = 0; t < 4; ++t) {
        int MT = t >> 1, NT = t & 1;
        int m = m0 + wm + MT * 16 + rbase;
        int n = n0 + wn + NT * 16 + cb;
        ushort4 o;
        o.x = f2bf(fmaxf(acc[t][0], 0.f));
        o.y = f2bf(fmaxf(acc[t][1], 0.f));
        o.z = f2bf(fmaxf(acc[t][2], 0.f));
        o.w = f2bf(fmaxf(acc[t][3], 0.f));
        *(ushort4*)(C + (size_t)n * M + m) = o;
    }
}

// ---------------------------------------------------------------------------
// L4 + score partials + loss-by-last-block. grid (8,17) = 136 blocks.
// ---------------------------------------------------------------------------
__global__ __launch_bounds__(256) void gemm4_score_loss(
    const unsigned short* __restrict__ A,
    const unsigned short* __restrict__ Bm,
    const float* __restrict__ W5, const int* __restrict__ rand_idx,
    float* __restrict__ zbuf, unsigned* __restrict__ done,
    float* __restrict__ out, int M, int K)
{
    __shared__ GemmS sh;
    __shared__ int s_flag;
    __shared__ int s_cnt[32];
    __shared__ float s_red[256];
    int m0 = blockIdx.x * 64, n0 = blockIdx.y * 64;
    f32x4 acc[4];
    gemm_core(A, Bm, K, m0, n0, sh, acc);
    int tid = threadIdx.x;
    int w = tid >> 6, lane = tid & 63;
    int wm = (w >> 1) * 32, wn = (w & 1) * 32;
    int fr = lane & 15, fq = lane >> 4;
    #pragma unroll
    for (int NT = 0; NT < 2; ++NT) {
        float p = 0.f;
        #pragma unroll
        for (int MT = 0; MT < 2; ++MT) {
            const f32x4 a = acc[MT * 2 + NT];
            int mb = m0 + wm + MT * 16 + fq * 4;
            p += fmaxf(a[0], 0.f) * W5[mb]
               + fmaxf(a[1], 0.f) * W5[mb + 1]
               + fmaxf(a[2], 0.f) * W5[mb + 2]
               + fmaxf(a[3], 0.f) * W5[mb + 3];
        }
        p += __shfl_down(p, 32);
        p += __shfl_down(p, 16);
        if (fq == 0) {
            int n = n0 + wn + NT * 16 + fr;
            atomicAdd(&zbuf[n], p);
        }
    }
    __syncthreads();   // drains vmcnt: this block's zbuf atomics complete
    if (tid == 0) {
        unsigned old = __hip_atomic_fetch_add(done, 1u, __ATOMIC_ACQ_REL,
                                              __HIP_MEMORY_SCOPE_AGENT);
        s_flag = (old == 8 * 17 - 1) ? 1 : 0;
    }
    __syncthreads();
    if (s_flag) {      // last block: all zbuf adds visible (acquire on done)
        if (tid < 32) s_cnt[tid] = 0;
        __syncthreads();
        if (tid < NEG_N_) atomicAdd(&s_cnt[rand_idx[tid]], 1);
        __syncthreads();
        float accv = 0.f;
        for (int c = tid; c < NCOL_; c += 256) {
            float z = __hip_atomic_load(&zbuf[c], __ATOMIC_ACQUIRE,
                                        __HIP_MEMORY_SCOPE_AGENT);
            float s = 1.f / (1.f + expf(-z));
            int c33 = c % 33;
            if (c33 == 0) { float d = s - 1.f; accv += 128.f * d * d; }
            else          { accv += (float)s_cnt[c33 - 1] * s * s; }
        }
        s_red[tid] = accv;
        __syncthreads();
        for (int o = 128; o > 0; o >>= 1) {
            if (tid < o) s_red[tid] += s_red[tid + o];
            __syncthreads();
        }
        if (tid == 0) out[0] = s_red[0];
    }
}

extern "C" void kernel_launch(void* const* d_in, const int* in_sizes, int n_in,
                              void* d_out, int out_size, void* d_ws, size_t ws_size,
                              hipStream_t stream)
{
    const int*   doc        = (const int*)d_in[0];
    const float* doc_f      = (const float*)d_in[1];
    const int*   query      = (const int*)d_in[2];
    const int*   target_s   = (const int*)d_in[3];
    const int*   target_e   = (const int*)d_in[4];
    const float* emb        = (const float*)d_in[7];
    const float* W1         = (const float*)d_in[8];
    const float* W2         = (const float*)d_in[9];
    const float* W3         = (const float*)d_in[10];
    const float* W4         = (const float*)d_in[11];
    const float* W5         = (const float*)d_in[12];
    const int*   rand_length   = (const int*)d_in[13];
    const int*   rand_position = (const int*)d_in[14];
    const int*   rand_idx      = (const int*)d_in[15];

    char* ws = (char*)d_ws;
    size_t off = 0;
    auto alloc = [&](size_t bytes) {
        void* p = ws + off;
        off = (off + bytes + 255) & ~(size_t)255;
        return p;
    };
    unsigned short* W1b = (unsigned short*)alloc((size_t)1024 * KP1_ * 2);
    unsigned short* W2b = (unsigned short*)alloc((size_t)1024 * 1024 * 2);
    unsigned short* W3b = (unsigned short*)alloc((size_t)1024 * 1024 * 2);
    unsigned short* W4b = (unsigned short*)alloc((size_t)512 * 1024 * 2);
    unsigned short* Ft  = (unsigned short*)alloc((size_t)NPAD_ * KP1_ * 2);
    unsigned short* hA  = (unsigned short*)alloc((size_t)NPAD_ * 1024 * 2);
    unsigned short* hB  = (unsigned short*)alloc((size_t)NPAD_ * 1024 * 2);
    float*    zbuf      = (float*)alloc((size_t)NPAD_ * sizeof(float));
    unsigned* done      = (unsigned*)alloc(256);
    (void)ws_size; (void)in_sizes; (void)n_in; (void)out_size;

    prep<<<dim3(2113), dim3(320), 0, stream>>>(
        doc, doc_f, query, target_s, target_e, emb,
        rand_length, rand_position,
        W1, W1b, Ft, zbuf, done);

    gemm_relu<<<dim3(336), dim3(256), 0, stream>>>(
        W1b, Ft, hA, 1024, KP1_, W2, W2b, 262144);
    gemm_relu<<<dim3(336), dim3(256), 0, stream>>>(
        W2b, hA, hB, 1024, 1024, W3, W3b, 262144);
    gemm_relu<<<dim3(336), dim3(256), 0, stream>>>(
        W3b, hB, hA, 1024, 1024, W4, W4b, 131072);
    gemm4_score_loss<<<dim3(8, 17), dim3(256), 0, stream>>>(
        W4b, hA, W5, rand_idx, zbuf, done, (float*)d_out, 512, 1024);
}